// Round 7
// baseline (159.048 us; speedup 1.0000x reference)
//
#include <hip/hip_runtime.h>

// out[i] = gen_map[x_gen[i]] + c * x_max_clock_speed[i] + d * x_max_tdp[i]
// N = 8388608 (2^23), NUM_GENS = 1024.
// Ledger: R1 46us, R2 44 (persistent: neutral), R4 42 (nt stores), R5 38
// (nt loads), R6 37 (SW pipeline: neutral). Exonerated: occupancy, LDS
// barrier, bank conflicts, L1-vs-LDS gather, MLP depth, VGPR squeeze.
// R7: isolate the store path — REGULAR stores (L2 write-back/combining,
// like the harness fills that hit 6.5 TB/s) instead of nt write-around;
// nt loads kept (proven +10%). Everything else identical to R6.

#define NUM_GENS 1024
#define BLOCK 256
#define GRID 1024

typedef float nfloat4 __attribute__((ext_vector_type(4)));
typedef int   nint4   __attribute__((ext_vector_type(4)));

__device__ __forceinline__ nfloat4 stage_compute(const float* s_map, float c, float d,
                                                 nint4 g, nfloat4 a, nfloat4 b) {
    nfloat4 o;
    o.x = s_map[g.x] + c * a.x + d * b.x;
    o.y = s_map[g.y] + c * a.y + d * b.y;
    o.z = s_map[g.z] + c * a.z + d * b.z;
    o.w = s_map[g.w] + c * a.w + d * b.w;
    return o;
}

__global__ __launch_bounds__(BLOCK, 4)
void Model_64364379898151_kernel(const int* __restrict__ x_gen,
                                 const float* __restrict__ x_clock,
                                 const float* __restrict__ x_tdp,
                                 const float* __restrict__ gen_map,
                                 const float* __restrict__ c_ptr,
                                 const float* __restrict__ d_ptr,
                                 float* __restrict__ out,
                                 int n_vec)  // number of vec4 groups
{
    __shared__ float s_map[NUM_GENS];
    ((float4*)s_map)[threadIdx.x] = ((const float4*)gen_map)[threadIdx.x];
    __syncthreads();

    const float c = c_ptr[0];
    const float d = d_ptr[0];

    const int stride = GRID * BLOCK;            // 262144 vec4 groups
    const int idx = blockIdx.x * BLOCK + threadIdx.x;

    const nint4*   g4 = (const nint4*)  x_gen;
    const nfloat4* c4 = (const nfloat4*)x_clock;
    const nfloat4* t4 = (const nfloat4*)x_tdp;
    nfloat4*       o4 = (nfloat4*)      out;

    if (n_vec == 8 * stride) {
        // Fast path for N = 2^23: exactly 8 vec4 groups per thread,
        // two 4-group stages, all 24 nt loads issued before any use.
        const int j0 = idx;
        const int j1 = idx + 1 * stride;
        const int j2 = idx + 2 * stride;
        const int j3 = idx + 3 * stride;
        const int j4 = idx + 4 * stride;
        const int j5 = idx + 5 * stride;
        const int j6 = idx + 6 * stride;
        const int j7 = idx + 7 * stride;

        // Stage A loads
        nint4   gA0 = __builtin_nontemporal_load(g4 + j0);
        nint4   gA1 = __builtin_nontemporal_load(g4 + j1);
        nint4   gA2 = __builtin_nontemporal_load(g4 + j2);
        nint4   gA3 = __builtin_nontemporal_load(g4 + j3);
        nfloat4 aA0 = __builtin_nontemporal_load(c4 + j0);
        nfloat4 aA1 = __builtin_nontemporal_load(c4 + j1);
        nfloat4 aA2 = __builtin_nontemporal_load(c4 + j2);
        nfloat4 aA3 = __builtin_nontemporal_load(c4 + j3);
        nfloat4 bA0 = __builtin_nontemporal_load(t4 + j0);
        nfloat4 bA1 = __builtin_nontemporal_load(t4 + j1);
        nfloat4 bA2 = __builtin_nontemporal_load(t4 + j2);
        nfloat4 bA3 = __builtin_nontemporal_load(t4 + j3);
        // Stage B loads (issued before stage A is consumed)
        nint4   gB0 = __builtin_nontemporal_load(g4 + j4);
        nint4   gB1 = __builtin_nontemporal_load(g4 + j5);
        nint4   gB2 = __builtin_nontemporal_load(g4 + j6);
        nint4   gB3 = __builtin_nontemporal_load(g4 + j7);
        nfloat4 aB0 = __builtin_nontemporal_load(c4 + j4);
        nfloat4 aB1 = __builtin_nontemporal_load(c4 + j5);
        nfloat4 aB2 = __builtin_nontemporal_load(c4 + j6);
        nfloat4 aB3 = __builtin_nontemporal_load(c4 + j7);
        nfloat4 bB0 = __builtin_nontemporal_load(t4 + j4);
        nfloat4 bB1 = __builtin_nontemporal_load(t4 + j5);
        nfloat4 bB2 = __builtin_nontemporal_load(t4 + j6);
        nfloat4 bB3 = __builtin_nontemporal_load(t4 + j7);

        // Regular stores: L2 write-back/combining path.
        o4[j0] = stage_compute(s_map, c, d, gA0, aA0, bA0);
        o4[j1] = stage_compute(s_map, c, d, gA1, aA1, bA1);
        o4[j2] = stage_compute(s_map, c, d, gA2, aA2, bA2);
        o4[j3] = stage_compute(s_map, c, d, gA3, aA3, bA3);
        o4[j4] = stage_compute(s_map, c, d, gB0, aB0, bB0);
        o4[j5] = stage_compute(s_map, c, d, gB1, aB1, bB1);
        o4[j6] = stage_compute(s_map, c, d, gB2, aB2, bB2);
        o4[j7] = stage_compute(s_map, c, d, gB3, aB3, bB3);
    } else {
        // Generic grid-stride fallback (not taken for N = 2^23).
        for (int i = idx; i < n_vec; i += stride) {
            nint4   g  = __builtin_nontemporal_load(g4 + i);
            nfloat4 cs = __builtin_nontemporal_load(c4 + i);
            nfloat4 td = __builtin_nontemporal_load(t4 + i);
            o4[i] = stage_compute(s_map, c, d, g, cs, td);
        }
    }
}

extern "C" void kernel_launch(void* const* d_in, const int* in_sizes, int n_in,
                              void* d_out, int out_size, void* d_ws, size_t ws_size,
                              hipStream_t stream) {
    // setup_inputs() order:
    // 0: x_gen (int32, N)         1: x_ix (int32, N) -- unused
    // 2: x_max_clock_speed (f32)  3: x_max_tdp (f32)
    // 4: gen_map (f32, 1024)
    // 5: b (f32 scalar, unused)   6: c (f32 scalar)   7: d (f32 scalar)
    const int*   x_gen   = (const int*)  d_in[0];
    const float* x_clock = (const float*)d_in[2];
    const float* x_tdp   = (const float*)d_in[3];
    const float* gen_map = (const float*)d_in[4];
    const float* c_ptr   = (const float*)d_in[6];
    const float* d_ptr   = (const float*)d_in[7];
    float* out = (float*)d_out;

    const int n = in_sizes[0];          // 8388608
    const int n_vec = n / 4;            // 2^21 vec4 groups

    Model_64364379898151_kernel<<<GRID, BLOCK, 0, stream>>>(
        x_gen, x_clock, x_tdp, gen_map, c_ptr, d_ptr, out, n_vec);
}

// Round 8
// 157.348 us; speedup vs baseline: 1.0108x; 1.0108x over previous
//
#include <hip/hip_runtime.h>

// out[i] = gen_map[x_gen[i]] + c * x_max_clock_speed[i] + d * x_max_tdp[i]
// N = 8388608 (2^23), NUM_GENS = 1024.
// Ledger: R1 46, R2 44, R4 42 (nt stores +5%), R5 38 (nt loads +10%),
// R6 37 (pipeline depth: neutral), R7 39 (regular stores: regression).
// R5 vs R6: waves/CU x MLP-depth product constant -> consistent with a
// per-CU outstanding-miss cap (~14 GB/s/CU sustained = ~5KB in flight at
// ~900cyc HBM latency).
// R8 (last untested lever): locality. Contiguous per-block chunks (each
// block owns 1024 consecutive vec4 groups = 16 KB/stream; stages adjacent
// -> DRAM page reuse) + XCD swizzle (each XCD's blocks cover a contiguous
// 1/8 of the address space). nt loads/stores + LDS gather kept.

#define NUM_GENS 1024
#define BLOCK 256
#define GRID 2048
#define GROUPS_PER_BLOCK 1024   // n_vec / GRID = 2^21 / 2048

typedef float nfloat4 __attribute__((ext_vector_type(4)));
typedef int   nint4   __attribute__((ext_vector_type(4)));

__device__ __forceinline__ nfloat4 stage_compute(const float* s_map, float c, float d,
                                                 nint4 g, nfloat4 a, nfloat4 b) {
    nfloat4 o;
    o.x = s_map[g.x] + c * a.x + d * b.x;
    o.y = s_map[g.y] + c * a.y + d * b.y;
    o.z = s_map[g.z] + c * a.z + d * b.z;
    o.w = s_map[g.w] + c * a.w + d * b.w;
    return o;
}

__global__ __launch_bounds__(BLOCK, 4)
void Model_64364379898151_kernel(const int* __restrict__ x_gen,
                                 const float* __restrict__ x_clock,
                                 const float* __restrict__ x_tdp,
                                 const float* __restrict__ gen_map,
                                 const float* __restrict__ c_ptr,
                                 const float* __restrict__ d_ptr,
                                 float* __restrict__ out,
                                 int n_vec)  // number of vec4 groups
{
    __shared__ float s_map[NUM_GENS];
    ((float4*)s_map)[threadIdx.x] = ((const float4*)gen_map)[threadIdx.x];
    __syncthreads();

    const float c = c_ptr[0];
    const float d = d_ptr[0];

    const nint4*   g4 = (const nint4*)  x_gen;
    const nfloat4* c4 = (const nfloat4*)x_clock;
    const nfloat4* t4 = (const nfloat4*)x_tdp;
    nfloat4*       o4 = (nfloat4*)      out;

    if (n_vec == GRID * GROUPS_PER_BLOCK) {
        // Fast path for N = 2^23.
        // XCD swizzle: HW dispatches block b to XCD b%8. Remap so each XCD's
        // blocks own one contiguous 1/8 of the address space.
        const int b       = blockIdx.x;
        const int logical = (b & 7) * (GRID / 8) + (b >> 3);
        const int base    = logical * GROUPS_PER_BLOCK + (int)threadIdx.x;

        // 4 stages, 256 groups apart (4 KB apart per stream): block walks a
        // contiguous 16 KB window per stream.
        const int j0 = base;
        const int j1 = base + 1 * BLOCK;
        const int j2 = base + 2 * BLOCK;
        const int j3 = base + 3 * BLOCK;

        nint4   g0 = __builtin_nontemporal_load(g4 + j0);
        nint4   g1 = __builtin_nontemporal_load(g4 + j1);
        nint4   g2 = __builtin_nontemporal_load(g4 + j2);
        nint4   g3 = __builtin_nontemporal_load(g4 + j3);
        nfloat4 a0 = __builtin_nontemporal_load(c4 + j0);
        nfloat4 a1 = __builtin_nontemporal_load(c4 + j1);
        nfloat4 a2 = __builtin_nontemporal_load(c4 + j2);
        nfloat4 a3 = __builtin_nontemporal_load(c4 + j3);
        nfloat4 b0 = __builtin_nontemporal_load(t4 + j0);
        nfloat4 b1 = __builtin_nontemporal_load(t4 + j1);
        nfloat4 b2 = __builtin_nontemporal_load(t4 + j2);
        nfloat4 b3 = __builtin_nontemporal_load(t4 + j3);

        __builtin_nontemporal_store(stage_compute(s_map, c, d, g0, a0, b0), o4 + j0);
        __builtin_nontemporal_store(stage_compute(s_map, c, d, g1, a1, b1), o4 + j1);
        __builtin_nontemporal_store(stage_compute(s_map, c, d, g2, a2, b2), o4 + j2);
        __builtin_nontemporal_store(stage_compute(s_map, c, d, g3, a3, b3), o4 + j3);
    } else {
        // Generic grid-stride fallback (not taken for N = 2^23).
        const int idx    = blockIdx.x * BLOCK + threadIdx.x;
        const int stride = GRID * BLOCK;
        for (int i = idx; i < n_vec; i += stride) {
            nint4   g  = __builtin_nontemporal_load(g4 + i);
            nfloat4 cs = __builtin_nontemporal_load(c4 + i);
            nfloat4 td = __builtin_nontemporal_load(t4 + i);
            __builtin_nontemporal_store(stage_compute(s_map, c, d, g, cs, td), o4 + i);
        }
    }
}

extern "C" void kernel_launch(void* const* d_in, const int* in_sizes, int n_in,
                              void* d_out, int out_size, void* d_ws, size_t ws_size,
                              hipStream_t stream) {
    // setup_inputs() order:
    // 0: x_gen (int32, N)         1: x_ix (int32, N) -- unused
    // 2: x_max_clock_speed (f32)  3: x_max_tdp (f32)
    // 4: gen_map (f32, 1024)
    // 5: b (f32 scalar, unused)   6: c (f32 scalar)   7: d (f32 scalar)
    const int*   x_gen   = (const int*)  d_in[0];
    const float* x_clock = (const float*)d_in[2];
    const float* x_tdp   = (const float*)d_in[3];
    const float* gen_map = (const float*)d_in[4];
    const float* c_ptr   = (const float*)d_in[6];
    const float* d_ptr   = (const float*)d_in[7];
    float* out = (float*)d_out;

    const int n = in_sizes[0];          // 8388608
    const int n_vec = n / 4;            // 2^21 vec4 groups

    Model_64364379898151_kernel<<<GRID, BLOCK, 0, stream>>>(
        x_gen, x_clock, x_tdp, gen_map, c_ptr, d_ptr, out, n_vec);
}